// Round 10
// baseline (88.067 us; speedup 1.0000x reference)
//
#include <hip/hip_runtime.h>
#include <float.h>
#include <limits.h>

// NearestCluster: per-batch NN argmin via uniform 8^3 grid (exact),
// with BOTH refs and queries sorted by cell.
// coords1 [L1=4096, N=8, C=3] f32 (reference), coords2 [L2=4096, N=8, C=3] f32 (query)
// out int32: [L2*N] argmin idx over L1 per batch, then [L2*N] batch idx.
//
// Numerics: bit-exact vs numpy f32 reference:
//   qq = (q0*q0 + q1*q1) + q2*q2         rr likewise (round each op, no fma)
//   dot = ((q0*r0) + (q1*r1)) + (q2*r2)
//   d2 = (qq + rr) - 2*dot  ==  fma(-2, dot, qq+rr)   (2*dot exact)
// Ties -> lowest ORIGINAL index: candidates carry orig idx; every update and
// merge is lexicographic on (d2, idx) -> scatter order irrelevant.
// cell = clamp(floor(x*8)): x*8 is exact (pow2) -> pruning bound exact.
//
// R10 post-mortem: coalescing the bin pipeline changed NOTHING (+2.3us = 2
// extra launch gaps) -> bin was ~6us all along; grid_nn is ~25-30us across
// THREE different structures (R7/R8/R9). Prime suspect: launch_bounds-forced
// VGPR caps (64/85) vs ~85+ live regs -> scratch spill in the inner loop
// (rule-#20 5x), plus ~1 query/wave overhead (18 cs loads, decode, 12 shfls).
// R11: sort QUERIES by cell too (same pipeline); NN kernel = 4 lanes/query,
// per-lane 9-section candidate stream (no decode, no runtime-indexed arrays),
// 2-step merge, ~45 VGPR, launch_bounds(128) with NO min-waves cap.
// Sorted order -> a wave's 16 queries span 1-4 adjacent cells -> overlapping
// candidate sets (L1 dedup) and correlated trip counts.
//
// Pruning exactness (unchanged): refs outside the 3^3 neighborhood have an
// axis gap > 1/8 => true d2 > lb = 0.015625 (exact). Computed-vs-true error
// <= ~3.6e-6; skip fallback only when lb > bd + 4e-6 => pruned points'
// COMPUTED d2 > bd => never argmin nor tie. Else: full 4096 rescan (exact).
//
// ws layout (1245696 B; harness ws ~268 MB):
//   csR[8][520] curR[8][512] csQ[8][520] curQ[8][512]
//   cellR u16[32768] cellQ u16[32768]
//   ptsR f4[8][4096] (x,y,z,origRefIdx)   ptsQ f4[8][4096] (x,y,z,origQueryIdx)
// Fallback to the verified R5 LDS brute-force kernel if ws too small.

constexpr int kL1 = 4096, kL2 = 4096, kN = 8;
constexpr int kCS = 520;
constexpr size_t kOffCurR = 8ull * kCS * 4;                   // 16640
constexpr size_t kOffCsQ  = kOffCurR + 8ull * 512 * 4;        // 33024
constexpr size_t kOffCurQ = kOffCsQ + 8ull * kCS * 4;         // 49664
constexpr size_t kOffCellR = kOffCurQ + 8ull * 512 * 4;       // 66048
constexpr size_t kOffCellQ = kOffCellR + 32768ull * 2;        // 131584
constexpr size_t kOffPtsR = kOffCellQ + 32768ull * 2;         // 197120
constexpr size_t kOffPtsQ = kOffPtsR + 8ull * 4096 * 16;      // 721408
constexpr size_t kWsBytes = kOffPtsQ + 8ull * 4096 * 16;      // 1245696

__device__ __forceinline__ float rr_exact(float x, float y, float z) {
  return __fadd_rn(__fadd_rn(__fmul_rn(x, x), __fmul_rn(y, y)), __fmul_rn(z, z));
}

__device__ __forceinline__ int cell_of(float x, float y, float z) {
  const int cx = min(7, max(0, (int)(x * 8.0f)));
  const int cy = min(7, max(0, (int)(y * 8.0f)));
  const int cz = min(7, max(0, (int)(z * 8.0f)));
  return (cz * 8 + cy) * 8 + cx;
}

// ---- K1: per-point cell ids for refs AND queries, fully coalesced ----
__global__ __launch_bounds__(256)
void cellof_kernel(const float* __restrict__ c1, const float* __restrict__ c2,
                   unsigned short* __restrict__ cellR,
                   unsigned short* __restrict__ cellQ) {
  const int t = blockIdx.x * 256 + threadIdx.x;   // 0..65535
  const int u = t & 32767;
  const float* p = (t < 32768 ? c1 : c2) + 3 * u;
  const int c = cell_of(p[0], p[1], p[2]);
  if (t < 32768) cellR[u] = (unsigned short)c;
  else cellQ[u] = (unsigned short)c;
}

// ---- K2: per-(batch, side) LDS histogram + scan -> cellStart, cursor ----
__global__ __launch_bounds__(1024)
void histscan_kernel(const unsigned short* __restrict__ cellR,
                     const unsigned short* __restrict__ cellQ,
                     int* __restrict__ csR, int* __restrict__ curR,
                     int* __restrict__ csQ, int* __restrict__ curQ) {
  __shared__ int hist[512];
  const int tid = threadIdx.x;
  const int n = blockIdx.x & 7;
  const bool isQ = blockIdx.x >= 8;
  const unsigned short* cof = isQ ? cellQ : cellR;
  int* cs = isQ ? csQ : csR;
  int* cur = isQ ? curQ : curR;
  if (tid < 512) hist[tid] = 0;
  __syncthreads();

#pragma unroll
  for (int k = 0; k < 4; ++k) {
    const int j = k * 1024 + tid;
    atomicAdd(&hist[cof[j * kN + n]], 1);
  }
  __syncthreads();

  if (tid < 64) {
    int loc[8], part = 0;
#pragma unroll
    for (int i = 0; i < 8; ++i) { loc[i] = hist[tid * 8 + i]; part += loc[i]; }
    int inc = part;
#pragma unroll
    for (int off = 1; off < 64; off <<= 1) {
      const int v = __shfl_up(inc, off);
      if (tid >= off) inc += v;
    }
    int base = inc - part;
#pragma unroll
    for (int i = 0; i < 8; ++i) {
      const int c = tid * 8 + i;
      cs[n * kCS + c] = base;
      cur[n * 512 + c] = base;
      base += loc[i];
    }
    if (tid == 0) cs[n * kCS + 512] = 4096;
  }
}

// ---- K3: scatter refs and queries into cell-ordered arrays ----
__global__ __launch_bounds__(256)
void scatter_kernel(const float* __restrict__ c1, const float* __restrict__ c2,
                    const unsigned short* __restrict__ cellR,
                    const unsigned short* __restrict__ cellQ,
                    int* __restrict__ curR, int* __restrict__ curQ,
                    float4* __restrict__ ptsR, float4* __restrict__ ptsQ) {
  const int t = blockIdx.x * 256 + threadIdx.x;   // 0..65535
  const int u = t & 32767;
  const bool isQ = t >= 32768;
  const float* p = (isQ ? c2 : c1) + 3 * u;
  const float x = p[0], y = p[1], z = p[2];
  const int n = u & 7, j = u >> 3;
  const int cell = (isQ ? cellQ : cellR)[u];
  int* cur = isQ ? curQ : curR;
  float4* pts = isQ ? ptsQ : ptsR;
  const int pos = atomicAdd(&cur[n * 512 + cell], 1);
  pts[n * 4096 + pos] = make_float4(x, y, z, __int_as_float(j));
}

// ---- K4: sorted-query NN. 4 lanes per query; per-lane 9-section stream ----
__global__ __launch_bounds__(128)
void cell_nn_kernel(const int* __restrict__ csR, const float4* __restrict__ ptsR,
                    const float4* __restrict__ ptsQ, int* __restrict__ out) {
#pragma clang fp contract(off)
  const int n = blockIdx.y;
  const int qslot = blockIdx.x * 32 + (threadIdx.x >> 2);  // sorted query slot
  const int sub = threadIdx.x & 3;

  const float4 qp = ptsQ[n * 4096 + qslot];    // coalesced (4 lanes same addr)
  const float qx = qp.x, qy = qp.y, qz = qp.z;
  const float qq = rr_exact(qx, qy, qz);
  const int cx = min(7, max(0, (int)(qx * 8.0f)));
  const int cy = min(7, max(0, (int)(qy * 8.0f)));
  const int cz = min(7, max(0, (int)(qz * 8.0f)));
  const int xlo = max(0, cx - 1), xhi = min(7, cx + 1);

  const int* __restrict__ cs = csR + n * kCS;
  const float4* __restrict__ P = ptsR + n * 4096;

  float bd = FLT_MAX;
  int bi = INT_MAX;

#pragma unroll
  for (int k = 0; k < 9; ++k) {                // unrolled: no runtime indexing
    const int dz = k / 3 - 1, dy = k % 3 - 1;
    const int z = cz + dz, y = cy + dy;
    const bool valid = ((unsigned)z <= 7u) && ((unsigned)y <= 7u);
    const int zc = min(7, max(0, z)), yc = min(7, max(0, y));
    const int row = (zc * 8 + yc) * 8;
    const int s = cs[row + xlo];
    const int e = valid ? cs[row + xhi + 1] : s;
    for (int p = s + sub; p < e; p += 4) {     // ~54 candidates per lane
      const float4 rp = P[p];
      const int id = __float_as_int(rp.w);
      const float rr = rr_exact(rp.x, rp.y, rp.z);
      const float dot = __fadd_rn(
          __fadd_rn(__fmul_rn(qx, rp.x), __fmul_rn(qy, rp.y)),
          __fmul_rn(qz, rp.z));
      const float d2 = __fmaf_rn(-2.0f, dot, __fadd_rn(qq, rr));
      if (d2 < bd || (d2 == bd && id < bi)) { bd = d2; bi = id; }
    }
  }

  // merge across the 4-lane group (lexicographic on (d2, idx))
#pragma unroll
  for (int m = 1; m <= 2; m <<= 1) {
    const float od = __shfl_xor(bd, m);
    const int oi = __shfl_xor(bi, m);
    if (od < bd || (od == bd && oi < bi)) { bd = od; bi = oi; }
  }

  // Fallback (rare; group-coherent): full exact rescan.
  if (!(0.015625f > __fadd_rn(bd, 4e-6f))) {
    for (int p = sub; p < kL1; p += 4) {
      const float4 rp = P[p];
      const int id = __float_as_int(rp.w);
      const float rr = rr_exact(rp.x, rp.y, rp.z);
      const float dot = __fadd_rn(
          __fadd_rn(__fmul_rn(qx, rp.x), __fmul_rn(qy, rp.y)),
          __fmul_rn(qz, rp.z));
      const float d2 = __fmaf_rn(-2.0f, dot, __fadd_rn(qq, rr));
      if (d2 < bd || (d2 == bd && id < bi)) { bd = d2; bi = id; }
    }
#pragma unroll
    for (int m = 1; m <= 2; m <<= 1) {
      const float od = __shfl_xor(bd, m);
      const int oi = __shfl_xor(bi, m);
      if (od < bd || (od == bd && oi < bi)) { bd = od; bi = oi; }
    }
  }

  if (sub == 0) {
    const int qj = __float_as_int(qp.w);       // original query index
    out[qj * kN + n] = bi;
    out[kL2 * kN + qj * kN + n] = n;
  }
}

// ---------------- Fallback (verified R5/R6 brute force, LDS) ----------------
constexpr int kQPerBlock = 16;
constexpr int kQ = 4;
constexpr int kChunk = 1024;

__global__ __launch_bounds__(256, 4)
void nearest_kernel_lds(const float* __restrict__ c1, const float* __restrict__ c2,
                        int* __restrict__ out) {
#pragma clang fp contract(off)
  __shared__ float sRx[kChunk], sRy[kChunk], sRz[kChunk], sRr[kChunk];
  const int tid = threadIdx.x;
  const int n = blockIdx.y;
  const int wave = tid >> 6;
  const int lane = tid & 63;
  const int q0 = blockIdx.x * kQPerBlock + wave * kQ;

  float qxs[kQ], qys[kQ], qzs[kQ], qqs[kQ];
#pragma unroll
  for (int i = 0; i < kQ; ++i) {
    const float* p = c2 + ((q0 + i) * kN + n) * 3;
    qxs[i] = p[0]; qys[i] = p[1]; qzs[i] = p[2];
    qqs[i] = rr_exact(qxs[i], qys[i], qzs[i]);
  }
  float bd[kQ]; int bt[kQ];
#pragma unroll
  for (int i = 0; i < kQ; ++i) { bd[i] = FLT_MAX; bt[i] = 0; }

  for (int chunk = 0; chunk < kL1 / kChunk; ++chunk) {
    __syncthreads();
    {
      const int jb = chunk * kChunk + tid * 4;
      float x[4], y[4], z[4], w4[4];
#pragma unroll
      for (int k = 0; k < 4; ++k) {
        const float* p = c1 + ((jb + k) * kN + n) * 3;
        x[k] = p[0]; y[k] = p[1]; z[k] = p[2];
        w4[k] = rr_exact(x[k], y[k], z[k]);
      }
      *reinterpret_cast<float4*>(&sRx[tid * 4]) = make_float4(x[0], x[1], x[2], x[3]);
      *reinterpret_cast<float4*>(&sRy[tid * 4]) = make_float4(y[0], y[1], y[2], y[3]);
      *reinterpret_cast<float4*>(&sRz[tid * 4]) = make_float4(z[0], z[1], z[2], z[3]);
      *reinterpret_cast<float4*>(&sRr[tid * 4]) = make_float4(w4[0], w4[1], w4[2], w4[3]);
    }
    __syncthreads();
#pragma unroll
    for (int t = 0; t < kChunk / 256; ++t) {
      const int tg = chunk * (kChunk / 256) + t;
      const int base = t * 256 + lane * 4;
      const float4 x4 = *reinterpret_cast<const float4*>(&sRx[base]);
      const float4 y4 = *reinterpret_cast<const float4*>(&sRy[base]);
      const float4 z4 = *reinterpret_cast<const float4*>(&sRz[base]);
      const float4 r4 = *reinterpret_cast<const float4*>(&sRr[base]);
      const float xs[4] = {x4.x, x4.y, x4.z, x4.w};
      const float ys[4] = {y4.x, y4.y, y4.z, y4.w};
      const float zs[4] = {z4.x, z4.y, z4.z, z4.w};
      const float rs[4] = {r4.x, r4.y, r4.z, r4.w};
#pragma unroll
      for (int i = 0; i < kQ; ++i) {
        float d[4];
#pragma unroll
        for (int k = 0; k < 4; ++k) {
          const float dot = __fadd_rn(
              __fadd_rn(__fmul_rn(qxs[i], xs[k]), __fmul_rn(qys[i], ys[k])),
              __fmul_rn(qzs[i], zs[k]));
          d[k] = __fmaf_rn(-2.0f, dot, __fadd_rn(qqs[i], rs[k]));
        }
        const float old = bd[i];
        float m = fminf(fminf(d[0], d[1]), old);
        m = fminf(fminf(d[2], d[3]), m);
        bd[i] = m;
        if (m < old) bt[i] = tg;
      }
    }
  }
  int sel[kQ];
#pragma unroll
  for (int i = 0; i < kQ; ++i) sel[i] = bt[i] * 64 + lane;
#pragma unroll
  for (int m = 1; m <= 32; m <<= 1) {
#pragma unroll
    for (int i = 0; i < kQ; ++i) {
      const float od = __shfl_xor(bd[i], m);
      const int os = __shfl_xor(sel[i], m);
      if (od < bd[i] || (od == bd[i] && os < sel[i])) { bd[i] = od; sel[i] = os; }
    }
  }
#pragma unroll
  for (int i = 0; i < kQ; ++i) {
    if (lane == i) {
      const int j0 = sel[i] * 4;
      float best = FLT_MAX; int kk = 0;
#pragma unroll
      for (int k = 0; k < 4; ++k) {
        const float* p = c1 + ((j0 + k) * kN + n) * 3;
        const float r0 = p[0], r1 = p[1], r2 = p[2];
        const float rr = rr_exact(r0, r1, r2);
        const float dot = __fadd_rn(
            __fadd_rn(__fmul_rn(qxs[i], r0), __fmul_rn(qys[i], r1)),
            __fmul_rn(qzs[i], r2));
        const float dc = __fmaf_rn(-2.0f, dot, __fadd_rn(qqs[i], rr));
        if (dc < best) { best = dc; kk = k; }
      }
      out[(q0 + i) * kN + n] = j0 + kk;
      out[kL2 * kN + (q0 + i) * kN + n] = n;
    }
  }
}

extern "C" void kernel_launch(void* const* d_in, const int* in_sizes, int n_in,
                              void* d_out, int out_size, void* d_ws, size_t ws_size,
                              hipStream_t stream) {
  const float* c1 = (const float*)d_in[0];
  const float* c2 = (const float*)d_in[1];
  int* out = (int*)d_out;
  if (d_ws != nullptr && ws_size >= kWsBytes) {
    int* csR = (int*)d_ws;
    int* curR = (int*)((char*)d_ws + kOffCurR);
    int* csQ = (int*)((char*)d_ws + kOffCsQ);
    int* curQ = (int*)((char*)d_ws + kOffCurQ);
    unsigned short* cellR = (unsigned short*)((char*)d_ws + kOffCellR);
    unsigned short* cellQ = (unsigned short*)((char*)d_ws + kOffCellQ);
    float4* ptsR = (float4*)((char*)d_ws + kOffPtsR);
    float4* ptsQ = (float4*)((char*)d_ws + kOffPtsQ);
    cellof_kernel<<<dim3(256), dim3(256), 0, stream>>>(c1, c2, cellR, cellQ);
    histscan_kernel<<<dim3(16), dim3(1024), 0, stream>>>(cellR, cellQ, csR, curR,
                                                         csQ, curQ);
    scatter_kernel<<<dim3(256), dim3(256), 0, stream>>>(c1, c2, cellR, cellQ,
                                                        curR, curQ, ptsR, ptsQ);
    cell_nn_kernel<<<dim3(128, 8), dim3(128), 0, stream>>>(csR, ptsR, ptsQ, out);
  } else {
    dim3 grid(kL2 / kQPerBlock, kN);
    nearest_kernel_lds<<<grid, dim3(256), 0, stream>>>(c1, c2, out);
  }
}